// Round 6
// baseline (165.160 us; speedup 1.0000x reference)
//
#include <hip/hip_runtime.h>
#include <stdint.h>

// Problem constants (B=16, A=3, H=W=76, ATTR=5+80=85)
// Input:  fp32, shape (16, 255, 76, 76)   = 23,566,080 floats (94.3 MB)
// Output: fp32, shape (16, 3, 76, 76, 85) = 23,566,080 floats (94.3 MB)
//
// R6 structure: wave-autonomous micro-tiles. Each wave transposes a
// 16-spatial x 85-attrib micro-tile through a PRIVATE 5440 B LDS slice.
// No __syncthreads anywhere -> no block-wide vmcnt(0) drain convoy.
// 5776 = 361 * 16 exactly; 48 channels * 361 = 17328 micro-tiles
// = 4332 blocks * 4 waves, exact cover, 5.4 KB work quantum.
#define NB      16
#define NA      3
#define S_TOT   5776
#define ATTR    85
#define MT_S    16                    // micro-tile spatial extent
#define MT_PER  361                   // micro-tiles per (b,a) channel
#define N_MT    (NB * NA * MT_PER)    // 17328
#define WPB     4                     // waves per block
#define NTHREADS 256
#define LOG2E   1.44269504088896340f

typedef __attribute__((ext_vector_type(4))) float float4v;

__device__ __forceinline__ float fast_sigmoid(float x) {
    float e = __builtin_amdgcn_exp2f(x * (-LOG2E));
    return __builtin_amdgcn_rcpf(1.0f + e);
}

__global__ __launch_bounds__(NTHREADS, 7)   // 7 waves/SIMD -> 7 blocks/CU (LDS-limited), caps VGPR at 72
void yolo_layer_kernel(const float* __restrict__ in,
                       float* __restrict__ out) {
    // 4 private per-wave slices, 16*85 floats each (5440 B); 21760 B/block -> 7 blocks/CU
    __shared__ __attribute__((aligned(16))) float lds[WPB * MT_S * ATTR];

    const int lane = threadIdx.x & 63;
    const int wave = threadIdx.x >> 6;
    const int g    = blockIdx.x * WPB + wave;       // micro-tile id, 0..17327 (exact)
    const int BA   = g / MT_PER;                    // channel (b*3 + a)
    const int m    = g - BA * MT_PER;               // micro-tile within channel
    const int a    = BA % NA;
    const int s0   = m * MT_S;                      // global spatial base

    // anchors (faithful to reference's off-by-one anchor_h indexing)
    const float aw = (a == 0) ? 10.0f : (a == 1) ? 13.0f : 16.0f;
    const float ah = (a == 0) ? 13.0f : (a == 1) ? 16.0f : 30.0f;
    const float cw = aw * (1.0f / 608.0f);
    const float ch = ah * (1.0f / 608.0f);

    float* L = lds + wave * (MT_S * ATTR);
    const float* inb = in + (size_t)BA * (ATTR * S_TOT) + s0;

    // ---------- loads: 6 x (16 k-rows x 16 floats), lane -> (k = lane/4 + 16i, c = lane&3)
    // k clamped to 84: clamped lanes load row 84's data and later write the SAME
    // values to the SAME LDS addresses as the legit k=84 lanes -> benign.
    const int c  = lane & 3;
    const int kb = lane >> 2;
    float4v v[6];
    #pragma unroll
    for (int i = 0; i < 6; ++i) {
        int kk = kb + 16 * i;
        kk = (kk > 84) ? 84 : kk;
        v[i] = *(const float4v*)(inb + (size_t)kk * S_TOT + c * 4);
    }

    // ---------- math + transpose-scatter into private LDS slice ----------
    #pragma unroll
    for (int i = 0; i < 6; ++i) {
        int kk = kb + 16 * i;
        kk = (kk > 84) ? 84 : kk;

        float r[4];
        if (kk >= 4) {
            #pragma unroll
            for (int j = 0; j < 4; ++j) r[j] = fast_sigmoid(v[i][j]);
        } else {
            // only i==0, lanes 0..15 ever take this
            #pragma unroll
            for (int j = 0; j < 4; ++j) {
                float x  = v[i][j];
                int   sp = s0 + c * 4 + j;          // global spatial = h*76 + w
                int   hy = sp / 76;
                int   wx = sp - hy * 76;
                if      (kk == 0) r[j] = ((float)wx + fast_sigmoid(x)) * (1.0f / 76.0f);
                else if (kk == 1) r[j] = ((float)hy + fast_sigmoid(x)) * (1.0f / 76.0f);
                else if (kk == 2) r[j] = __builtin_amdgcn_exp2f(x * LOG2E) * cw;
                else              r[j] = __builtin_amdgcn_exp2f(x * LOG2E) * ch;
            }
        }

        float* lp = &L[c * 4 * ATTR + kk];
        #pragma unroll
        for (int j = 0; j < 4; ++j) lp[j * ATTR] = r[j];
    }

    // ---------- contiguous read-back + NT store (intra-wave lgkmcnt ordering only) ----------
    // out span: 16*85 = 1360 floats = 340 float4s, base 16B-aligned (5440*m etc.)
    float4v* outv = (float4v*)(out + ((size_t)BA * S_TOT + s0) * ATTR);
    const float4v* Lv = (const float4v*)L;
    #pragma unroll
    for (int i = 0; i < 6; ++i) {
        int idx = lane + 64 * i;
        if (idx < MT_S * ATTR / 4) {               // 340; only i==5 partially masked
            __builtin_nontemporal_store(Lv[idx], &outv[idx]);
        }
    }
}

extern "C" void kernel_launch(void* const* d_in, const int* in_sizes, int n_in,
                              void* d_out, int out_size, void* d_ws, size_t ws_size,
                              hipStream_t stream) {
    const float* in = (const float*)d_in[0];   // fp32 input
    float* out = (float*)d_out;                // fp32 output

    dim3 grid(N_MT / WPB);   // 4332 blocks x 4 waves = 17328 micro-tiles, exact
    dim3 block(NTHREADS);
    yolo_layer_kernel<<<grid, block, 0, stream>>>(in, out);
}